// Round 1
// baseline (799.058 us; speedup 1.0000x reference)
//
#include <hip/hip_runtime.h>
#include <math.h>

// EWRLS level filter. Recurrence collapses to a pure decay scan:
//   S_t = lam*S_{t-1} + x_t,  Q_t = lam*Q_{t-1} + 1,  y_t = S_t / Q_t
//
// R3 -> R4: fuse the two-kernel (carry, out) structure into ONE pass with
// decoupled lookback (rocPRIM pattern). x-chunk held in registers -> x is
// read from HBM exactly once (3 passes -> 2 passes + 4 MiB carries).
// Safety: atomic-ticket block ordering (a block only waits on strictly
// smaller tickets => owners already resident => deadlock-free regardless
// of dispatch order) + agent-scope atomics for cross-XCD coherence.

namespace {
constexpr int kB = 64;
constexpr int kT = 1024;
constexpr int kC = 512;
constexpr int kNCH = 32;             // chunks along T
constexpr int kL = kT / kNCH;        // 32 steps per chunk
constexpr int kCV = kC / 4;          // 128 float4 lanes per row
constexpr int kChunks = kB * kNCH;   // 2048
// ws layout (bytes):
//   [0]      uint ticket counter
//   [1024]   uint flags[kChunks]            (8 KiB)
//   [65536]  vfloat4 carry[kChunks][kCV]    (4 MiB)
constexpr size_t kFlagsOffB = 1024;
constexpr size_t kCarryOffB = 65536;
}

typedef float vfloat4 __attribute__((ext_vector_type(4)));

__device__ __forceinline__ void load_lam(const float* __restrict__ zl, int c0,
                                         float lam[4]) {
  vfloat4 z = *reinterpret_cast<const vfloat4*>(zl + c0);
#pragma unroll
  for (int k = 0; k < 4; ++k) {
    float s = 1.0f / (1.0f + expf(-z[k]));
    lam[k] = fminf(fmaxf(s, 1e-4f), 1.0f - 1e-4f);
  }
}

// Zero ticket + flags (workspace is poisoned between iterations).
extern "C" __global__ __launch_bounds__(256) void ewrls_init(
    unsigned* __restrict__ ws) {
  int i = blockIdx.x * 256 + threadIdx.x;
  if (i == 0) ws[0] = 0u;
  if (i < kChunks) ws[kFlagsOffB / 4 + i] = 0u;
}

// Single-pass chunked scan with decoupled lookback.
// Block = 256 threads = 2 chunks (c = 2*ticket, 2*ticket+1).
// Chunk linear id c = j*kB + b  (j-major so predecessors have smaller c,
// hence strictly smaller tickets).
extern "C" __global__ __launch_bounds__(256, 2) void ewrls_fused(
    const float* __restrict__ x, const float* __restrict__ zl,
    unsigned* __restrict__ ws, float* __restrict__ y) {
  __shared__ unsigned sh_vt;
  if (threadIdx.x == 0)
    sh_vt = __hip_atomic_fetch_add(ws, 1u, __ATOMIC_RELAXED,
                                   __HIP_MEMORY_SCOPE_AGENT);
  __syncthreads();
  const unsigned c = 2u * sh_vt + (threadIdx.x >> 7);
  const int j = (int)(c >> 6);       // c / kB
  const int b = (int)(c & 63u);      // c % kB
  const int cv = threadIdx.x & 127;

  unsigned* __restrict__ flags = ws + kFlagsOffB / 4;
  vfloat4* __restrict__ carry =
      reinterpret_cast<vfloat4*>(reinterpret_cast<char*>(ws) + kCarryOffB);

  float lam[4];
  load_lam(zl, cv * 4, lam);

  // Issue the whole x-chunk into registers (32 x float4 = 128 VGPR).
  const size_t base = ((size_t)b * kT + (size_t)j * kL) * kCV + cv;
  const vfloat4* xp = reinterpret_cast<const vfloat4*>(x) + base;
  vfloat4 xs[kL];
#pragma unroll
  for (int t = 0; t < kL; ++t) xs[t] = xp[(size_t)t * kCV];

  // Local decayed aggregate over the chunk.
  float a0 = 0.f, a1 = 0.f, a2 = 0.f, a3 = 0.f;
#pragma unroll
  for (int t = 0; t < kL; ++t) {
    a0 = fmaf(lam[0], a0, xs[t].x);
    a1 = fmaf(lam[1], a1, xs[t].y);
    a2 = fmaf(lam[2], a2, xs[t].z);
    a3 = fmaf(lam[3], a3, xs[t].w);
  }

  // Publish aggregate: relaxed agent-scope data stores, then (after the
  // block barrier) a release agent-scope flag store. Agent scope makes the
  // stores coherent across XCDs (through the shared L3).
  {
    union { vfloat4 v; unsigned long long u[2]; } pk;
    pk.v.x = a0; pk.v.y = a1; pk.v.z = a2; pk.v.w = a3;
    unsigned long long* p = reinterpret_cast<unsigned long long*>(
        carry + ((size_t)c * kCV + cv));
    __hip_atomic_store(p + 0, pk.u[0], __ATOMIC_RELAXED,
                       __HIP_MEMORY_SCOPE_AGENT);
    __hip_atomic_store(p + 1, pk.u[1], __ATOMIC_RELAXED,
                       __HIP_MEMORY_SCOPE_AGENT);
  }
  __syncthreads();
  if ((threadIdx.x & 127) == 0)
    __hip_atomic_store(flags + c, 1u, __ATOMIC_RELEASE,
                       __HIP_MEMORY_SCOPE_AGENT);

  // lam^kL for the fold.
  float lamL[4];
#pragma unroll
  for (int k = 0; k < 4; ++k) {
    float p = lam[k];
#pragma unroll
    for (int q = 0; q < 5; ++q) p = p * p;   // lam^32
    lamL[k] = p;
  }

  // Lookback: fold all predecessor aggregates (ascending i keeps the same
  // fma-fold as the verified R3 kernel). Waits only on smaller tickets.
  float S0 = 0.f, S1 = 0.f, S2 = 0.f, S3 = 0.f;
  float p0 = 1.f, p1 = 1.f, p2 = 1.f, p3 = 1.f;
  for (int i = 0; i < j; ++i) {
    const unsigned ci = (unsigned)(i * kB + b);
    while (__hip_atomic_load(flags + ci, __ATOMIC_ACQUIRE,
                             __HIP_MEMORY_SCOPE_AGENT) == 0u)
      __builtin_amdgcn_s_sleep(2);
    union { vfloat4 v; unsigned long long u[2]; } pk;
    const unsigned long long* p = reinterpret_cast<const unsigned long long*>(
        carry + ((size_t)ci * kCV + cv));
    pk.u[0] = __hip_atomic_load(p + 0, __ATOMIC_RELAXED,
                                __HIP_MEMORY_SCOPE_AGENT);
    pk.u[1] = __hip_atomic_load(p + 1, __ATOMIC_RELAXED,
                                __HIP_MEMORY_SCOPE_AGENT);
    S0 = fmaf(lamL[0], S0, pk.v.x);
    S1 = fmaf(lamL[1], S1, pk.v.y);
    S2 = fmaf(lamL[2], S2, pk.v.z);
    S3 = fmaf(lamL[3], S3, pk.v.w);
    p0 *= lamL[0];
    p1 *= lamL[1];
    p2 *= lamL[2];
    p3 *= lamL[3];
  }

  // Seed Q from closed form: Q_{j*kL-1} = (1 - lam^(j*kL)) / (1 - lam).
  float Q0 = (1.0f - p0) * __builtin_amdgcn_rcpf(1.0f - lam[0]);
  float Q1 = (1.0f - p1) * __builtin_amdgcn_rcpf(1.0f - lam[1]);
  float Q2 = (1.0f - p2) * __builtin_amdgcn_rcpf(1.0f - lam[2]);
  float Q3 = (1.0f - p3) * __builtin_amdgcn_rcpf(1.0f - lam[3]);

  // Output pass straight from registers (no x re-read).
  vfloat4* yp = reinterpret_cast<vfloat4*>(y) + base;
#pragma unroll
  for (int t = 0; t < kL; ++t) {
    S0 = fmaf(lam[0], S0, xs[t].x);
    S1 = fmaf(lam[1], S1, xs[t].y);
    S2 = fmaf(lam[2], S2, xs[t].z);
    S3 = fmaf(lam[3], S3, xs[t].w);
    Q0 = fmaf(lam[0], Q0, 1.0f);
    Q1 = fmaf(lam[1], Q1, 1.0f);
    Q2 = fmaf(lam[2], Q2, 1.0f);
    Q3 = fmaf(lam[3], Q3, 1.0f);
    vfloat4 o;
    o.x = S0 * __builtin_amdgcn_rcpf(Q0);
    o.y = S1 * __builtin_amdgcn_rcpf(Q1);
    o.z = S2 * __builtin_amdgcn_rcpf(Q2);
    o.w = S3 * __builtin_amdgcn_rcpf(Q3);
    __builtin_nontemporal_store(o, &yp[(size_t)t * kCV]);
  }
}

// Fallback if workspace is too small: fully sequential over T per (b, 4ch).
extern "C" __global__ __launch_bounds__(256) void ewrls_serial(
    const float* __restrict__ x, const float* __restrict__ zl,
    float* __restrict__ y) {
  int idx = blockIdx.x * 256 + threadIdx.x;   // [0, kB*kCV)
  int cv = idx % kCV;
  int b = idx / kCV;
  float lam[4];
  load_lam(zl, cv * 4, lam);
  float S[4] = {0.f, 0.f, 0.f, 0.f};
  float Q[4] = {0.f, 0.f, 0.f, 0.f};
  const size_t base = (size_t)b * kT * kCV + cv;
  const vfloat4* xp = reinterpret_cast<const vfloat4*>(x) + base;
  vfloat4* yp = reinterpret_cast<vfloat4*>(y) + base;
#pragma unroll 4
  for (int t = 0; t < kT; ++t) {
    vfloat4 v = xp[(size_t)t * kCV];
    S[0] = fmaf(lam[0], S[0], v.x);
    S[1] = fmaf(lam[1], S[1], v.y);
    S[2] = fmaf(lam[2], S[2], v.z);
    S[3] = fmaf(lam[3], S[3], v.w);
    Q[0] = fmaf(lam[0], Q[0], 1.0f);
    Q[1] = fmaf(lam[1], Q[1], 1.0f);
    Q[2] = fmaf(lam[2], Q[2], 1.0f);
    Q[3] = fmaf(lam[3], Q[3], 1.0f);
    vfloat4 o;
    o.x = S[0] * __builtin_amdgcn_rcpf(Q[0]);
    o.y = S[1] * __builtin_amdgcn_rcpf(Q[1]);
    o.z = S[2] * __builtin_amdgcn_rcpf(Q[2]);
    o.w = S[3] * __builtin_amdgcn_rcpf(Q[3]);
    yp[(size_t)t * kCV] = o;
  }
}

extern "C" void kernel_launch(void* const* d_in, const int* in_sizes, int n_in,
                              void* d_out, int out_size, void* d_ws,
                              size_t ws_size, hipStream_t stream) {
  const float* x = (const float*)d_in[0];
  const float* zl = (const float*)d_in[1];
  float* y = (float*)d_out;

  const size_t need =
      kCarryOffB + (size_t)kChunks * kCV * sizeof(vfloat4);  // ~4.06 MiB
  if (ws_size >= need) {
    unsigned* ws = (unsigned*)d_ws;
    ewrls_init<<<(kChunks + 255) / 256, 256, 0, stream>>>(ws);
    ewrls_fused<<<kChunks / 2, 256, 0, stream>>>(x, zl, ws, y);
  } else {
    const int n = kB * kCV;                 // 8192 -> 32 blocks
    ewrls_serial<<<n / 256, 256, 0, stream>>>(x, zl, y);
  }
}

// Round 2
// 415.364 us; speedup vs baseline: 1.9238x; 1.9238x over previous
//
#include <hip/hip_runtime.h>
#include <math.h>

// EWRLS level filter. Recurrence collapses to a pure decay scan:
//   S_t = lam*S_{t-1} + x_t,  Q_t = lam*Q_{t-1} + 1,  y_t = S_t / Q_t
//
// R4 -> R5: same single-pass decoupled-lookback algorithm, two perf fixes:
//  1. No VGPR cap (R4's __launch_bounds__(256,2) forced 128 VGPR -> ~40
//     regs/thread spilled to scratch; WRITE_SIZE showed +38MB of spill).
//  2. Spin loops poll with RELAXED atomics (R4's ACQUIRE polls emitted a
//     cache-invalidate per poll -> invalidation storm, 350 GB/s effective).
//     One acquire fence after all flags observed; publisher does relaxed
//     data stores + one release fence + relaxed flag store.
//  3. Wave-granular work units (64 lanes = half a chunk's channels): each
//     wave tickets independently, publishes its own carry slice + flag.
//     No __syncthreads coupling; flags publish ASAP.
// Deadlock-free: a wave only waits on strictly smaller tickets; those
// owners are resident and their publish path is wait-free.

namespace {
constexpr int kB = 64;
constexpr int kT = 1024;
constexpr int kC = 512;
constexpr int kNCH = 32;              // chunks along T
constexpr int kL = kT / kNCH;         // 32 steps per chunk
constexpr int kCV = kC / 4;           // 128 float4 lanes per row
constexpr int kChunks = kB * kNCH;    // 2048
constexpr int kWUnits = kChunks * 2;  // 4096 wave units (chunk x half-C)
// ws layout (bytes):
//   [0]      uint ticket counter
//   [1024]   uint flags[kWUnits]            (16 KiB)
//   [65536]  vfloat4 carry[kChunks][kCV]    (4 MiB)
constexpr size_t kFlagsOffB = 1024;
constexpr size_t kCarryOffB = 65536;
}

typedef float vfloat4 __attribute__((ext_vector_type(4)));

__device__ __forceinline__ void load_lam(const float* __restrict__ zl, int c0,
                                         float lam[4]) {
  vfloat4 z = *reinterpret_cast<const vfloat4*>(zl + c0);
#pragma unroll
  for (int k = 0; k < 4; ++k) {
    float s = 1.0f / (1.0f + expf(-z[k]));
    lam[k] = fminf(fmaxf(s, 1e-4f), 1.0f - 1e-4f);
  }
}

// Zero ticket + flags (workspace is poisoned between iterations).
extern "C" __global__ __launch_bounds__(256) void ewrls_init(
    unsigned* __restrict__ ws) {
  int i = blockIdx.x * 256 + threadIdx.x;
  if (i == 0) ws[0] = 0u;
  if (i < kWUnits) ws[kFlagsOffB / 4 + i] = 0u;
}

// Single-pass chunked scan with decoupled lookback, wave-granular.
// wave unit wid = j*128 + b*2 + h  (j-major: predecessors of (j,b,h) are
// (i<j,b,h) -> strictly smaller wid -> strictly smaller ticket).
extern "C" __global__ __launch_bounds__(256) void ewrls_fused(
    const float* __restrict__ x, const float* __restrict__ zl,
    unsigned* __restrict__ ws, float* __restrict__ y) {
  unsigned t0 = 0;
  if ((threadIdx.x & 63) == 0)
    t0 = __hip_atomic_fetch_add(ws, 1u, __ATOMIC_RELAXED,
                                __HIP_MEMORY_SCOPE_AGENT);
  const unsigned wid = __builtin_amdgcn_readfirstlane(t0);
  const int j = (int)(wid >> 7);        // chunk along T
  const int bh = (int)(wid & 127u);     // b*2 + half
  const int b = bh >> 1;
  const int cv = ((bh & 1) << 6) | (int)(threadIdx.x & 63);

  unsigned* __restrict__ flags = ws + kFlagsOffB / 4;
  vfloat4* __restrict__ carry =
      reinterpret_cast<vfloat4*>(reinterpret_cast<char*>(ws) + kCarryOffB);

  float lam[4];
  load_lam(zl, cv * 4, lam);

  // Whole x-chunk slice into registers (32 x float4 = 128 VGPR).
  // Nontemporal: single-use data, keep L2 clean for carries/flags.
  const size_t base = ((size_t)b * kT + (size_t)j * kL) * kCV + cv;
  const vfloat4* xp = reinterpret_cast<const vfloat4*>(x) + base;
  vfloat4 xs[kL];
#pragma unroll
  for (int t = 0; t < kL; ++t)
    xs[t] = __builtin_nontemporal_load(&xp[(size_t)t * kCV]);

  // Local decayed aggregate.
  float a0 = 0.f, a1 = 0.f, a2 = 0.f, a3 = 0.f;
#pragma unroll
  for (int t = 0; t < kL; ++t) {
    a0 = fmaf(lam[0], a0, xs[t].x);
    a1 = fmaf(lam[1], a1, xs[t].y);
    a2 = fmaf(lam[2], a2, xs[t].z);
    a3 = fmaf(lam[3], a3, xs[t].w);
  }

  // Publish: relaxed agent-scope data stores -> one release fence (waits
  // this wave's vmem, writes back to coherence point) -> relaxed flag.
  const size_t cidx = ((size_t)j * kB + b) * kCV + cv;
  {
    union { vfloat4 v; unsigned long long u[2]; } pk;
    pk.v.x = a0; pk.v.y = a1; pk.v.z = a2; pk.v.w = a3;
    unsigned long long* p =
        reinterpret_cast<unsigned long long*>(carry + cidx);
    __hip_atomic_store(p + 0, pk.u[0], __ATOMIC_RELAXED,
                       __HIP_MEMORY_SCOPE_AGENT);
    __hip_atomic_store(p + 1, pk.u[1], __ATOMIC_RELAXED,
                       __HIP_MEMORY_SCOPE_AGENT);
  }
  __builtin_amdgcn_fence(__ATOMIC_RELEASE, "agent");
  if ((threadIdx.x & 63) == 0)
    __hip_atomic_store(flags + wid, 1u, __ATOMIC_RELAXED,
                       __HIP_MEMORY_SCOPE_AGENT);

  // lam^kL for the fold.
  float lamL[4];
#pragma unroll
  for (int k = 0; k < 4; ++k) {
    float p = lam[k];
#pragma unroll
    for (int q = 0; q < 5; ++q) p = p * p;   // lam^32
    lamL[k] = p;
  }

  // Wait phase: RELAXED polls (no per-poll invalidate; agent-scope atomics
  // read the coherence point). All 64 lanes poll the same address -> one
  // broadcast transaction per wave per poll.
  for (int i = 0; i < j; ++i) {
    const unsigned fid = ((unsigned)i << 7) | (unsigned)bh;
    while (__hip_atomic_load(flags + fid, __ATOMIC_RELAXED,
                             __HIP_MEMORY_SCOPE_AGENT) == 0u)
      __builtin_amdgcn_s_sleep(2);
  }
  if (j) __builtin_amdgcn_fence(__ATOMIC_ACQUIRE, "agent");

  // Fold predecessor aggregates (ascending i = verified R3 fma-fold).
  float S0 = 0.f, S1 = 0.f, S2 = 0.f, S3 = 0.f;
  float p0 = 1.f, p1 = 1.f, p2 = 1.f, p3 = 1.f;
  for (int i = 0; i < j; ++i) {
    union { vfloat4 v; unsigned long long u[2]; } pk;
    const unsigned long long* p = reinterpret_cast<const unsigned long long*>(
        carry + (((size_t)i * kB + b) * kCV + cv));
    pk.u[0] = __hip_atomic_load(p + 0, __ATOMIC_RELAXED,
                                __HIP_MEMORY_SCOPE_AGENT);
    pk.u[1] = __hip_atomic_load(p + 1, __ATOMIC_RELAXED,
                                __HIP_MEMORY_SCOPE_AGENT);
    S0 = fmaf(lamL[0], S0, pk.v.x);
    S1 = fmaf(lamL[1], S1, pk.v.y);
    S2 = fmaf(lamL[2], S2, pk.v.z);
    S3 = fmaf(lamL[3], S3, pk.v.w);
    p0 *= lamL[0];
    p1 *= lamL[1];
    p2 *= lamL[2];
    p3 *= lamL[3];
  }

  // Seed Q from closed form: Q_{j*kL-1} = (1 - lam^(j*kL)) / (1 - lam).
  float Q0 = (1.0f - p0) * __builtin_amdgcn_rcpf(1.0f - lam[0]);
  float Q1 = (1.0f - p1) * __builtin_amdgcn_rcpf(1.0f - lam[1]);
  float Q2 = (1.0f - p2) * __builtin_amdgcn_rcpf(1.0f - lam[2]);
  float Q3 = (1.0f - p3) * __builtin_amdgcn_rcpf(1.0f - lam[3]);

  // Output pass straight from registers (no x re-read).
  vfloat4* yp = reinterpret_cast<vfloat4*>(y) + base;
#pragma unroll
  for (int t = 0; t < kL; ++t) {
    S0 = fmaf(lam[0], S0, xs[t].x);
    S1 = fmaf(lam[1], S1, xs[t].y);
    S2 = fmaf(lam[2], S2, xs[t].z);
    S3 = fmaf(lam[3], S3, xs[t].w);
    Q0 = fmaf(lam[0], Q0, 1.0f);
    Q1 = fmaf(lam[1], Q1, 1.0f);
    Q2 = fmaf(lam[2], Q2, 1.0f);
    Q3 = fmaf(lam[3], Q3, 1.0f);
    vfloat4 o;
    o.x = S0 * __builtin_amdgcn_rcpf(Q0);
    o.y = S1 * __builtin_amdgcn_rcpf(Q1);
    o.z = S2 * __builtin_amdgcn_rcpf(Q2);
    o.w = S3 * __builtin_amdgcn_rcpf(Q3);
    __builtin_nontemporal_store(o, &yp[(size_t)t * kCV]);
  }
}

// Fallback if workspace is too small: fully sequential over T per (b, 4ch).
extern "C" __global__ __launch_bounds__(256) void ewrls_serial(
    const float* __restrict__ x, const float* __restrict__ zl,
    float* __restrict__ y) {
  int idx = blockIdx.x * 256 + threadIdx.x;   // [0, kB*kCV)
  int cv = idx % kCV;
  int b = idx / kCV;
  float lam[4];
  load_lam(zl, cv * 4, lam);
  float S[4] = {0.f, 0.f, 0.f, 0.f};
  float Q[4] = {0.f, 0.f, 0.f, 0.f};
  const size_t base = (size_t)b * kT * kCV + cv;
  const vfloat4* xp = reinterpret_cast<const vfloat4*>(x) + base;
  vfloat4* yp = reinterpret_cast<vfloat4*>(y) + base;
#pragma unroll 4
  for (int t = 0; t < kT; ++t) {
    vfloat4 v = xp[(size_t)t * kCV];
    S[0] = fmaf(lam[0], S[0], v.x);
    S[1] = fmaf(lam[1], S[1], v.y);
    S[2] = fmaf(lam[2], S[2], v.z);
    S[3] = fmaf(lam[3], S[3], v.w);
    Q[0] = fmaf(lam[0], Q[0], 1.0f);
    Q[1] = fmaf(lam[1], Q[1], 1.0f);
    Q[2] = fmaf(lam[2], Q[2], 1.0f);
    Q[3] = fmaf(lam[3], Q[3], 1.0f);
    vfloat4 o;
    o.x = S[0] * __builtin_amdgcn_rcpf(Q[0]);
    o.y = S[1] * __builtin_amdgcn_rcpf(Q[1]);
    o.z = S[2] * __builtin_amdgcn_rcpf(Q[2]);
    o.w = S[3] * __builtin_amdgcn_rcpf(Q[3]);
    yp[(size_t)t * kCV] = o;
  }
}

extern "C" void kernel_launch(void* const* d_in, const int* in_sizes, int n_in,
                              void* d_out, int out_size, void* d_ws,
                              size_t ws_size, hipStream_t stream) {
  const float* x = (const float*)d_in[0];
  const float* zl = (const float*)d_in[1];
  float* y = (float*)d_out;

  const size_t need =
      kCarryOffB + (size_t)kChunks * kCV * sizeof(vfloat4);  // ~4.06 MiB
  if (ws_size >= need) {
    unsigned* ws = (unsigned*)d_ws;
    ewrls_init<<<(kWUnits + 255) / 256, 256, 0, stream>>>(ws);
    ewrls_fused<<<kWUnits / 4, 256, 0, stream>>>(x, zl, ws, y);
  } else {
    const int n = kB * kCV;                 // 8192 -> 32 blocks
    ewrls_serial<<<n / 256, 256, 0, stream>>>(x, zl, y);
  }
}

// Round 3
// 257.466 us; speedup vs baseline: 3.1035x; 1.6133x over previous
//
#include <hip/hip_runtime.h>
#include <math.h>

// EWRLS level filter. Recurrence collapses to a pure decay scan:
//   S_t = lam*S_{t-1} + x_t,  Q_t = lam*Q_{t-1} + 1,  y_t = S_t / Q_t
//
// R5 -> R6: decoupled lookback, fence-FREE.
//  1. Carry values are published as packed (flag<<32 | float_bits) in ONE
//     64-bit relaxed agent-scope atomic. Flag travels with data -> no
//     release/acquire fences at all (R5 spent its time in per-wave
//     buffer_wbl2 / buffer_inv L2 drains).
//  2. No xs[] register staging (R5: 128 VGPR -> 3 waves/SIMD, 10% occ).
//     Phase A reads x with caching loads (fills L2/L3; R5's FETCH=79MB <
//     |x|=134MB proves re-reads are cache-absorbed); phase B re-reads with
//     nt loads. VGPR ~48 -> full residency of all 512 blocks.
//  3. Chunk kL 32->64: half the sync units (1024 chunks, lookback <= 15),
//     one ticket per BLOCK (512 RMWs total, broadcast via LDS).
// Deadlock-free: block ticket T waits only on chunks owned by tickets < T;
// ticket holders are resident and their publish path has no waits.

namespace {
constexpr int kB = 64;
constexpr int kT = 1024;
constexpr int kC = 512;
constexpr int kNCH = 16;              // chunks along T
constexpr int kL = kT / kNCH;         // 64 steps per chunk
constexpr int kCV = kC / 4;           // 128 float4 lanes per row
constexpr int kChunks = kB * kNCH;    // 1024
constexpr int kBlocks = kChunks / 2;  // 512 (2 chunks per 256-thr block)
// ws layout (bytes):
//   [0]      uint ticket counter
//   [1024]   u64 carry[kChunks][kCV][4]   (4 MiB) packed (flag<<32 | bits)
constexpr size_t kCarryOffB = 1024;
constexpr size_t kCarryU64 = (size_t)kChunks * kCV * 4;  // 524288
}

typedef float vfloat4 __attribute__((ext_vector_type(4)));

__device__ __forceinline__ void load_lam(const float* __restrict__ zl, int c0,
                                         float lam[4]) {
  vfloat4 z = *reinterpret_cast<const vfloat4*>(zl + c0);
#pragma unroll
  for (int k = 0; k < 4; ++k) {
    float s = 1.0f / (1.0f + expf(-z[k]));
    lam[k] = fminf(fmaxf(s, 1e-4f), 1.0f - 1e-4f);
  }
}

__device__ __forceinline__ float poll_val(
    const unsigned long long* __restrict__ p) {
  unsigned long long u = __hip_atomic_load(p, __ATOMIC_RELAXED,
                                           __HIP_MEMORY_SCOPE_AGENT);
  while (!(u >> 32)) {
    __builtin_amdgcn_s_sleep(1);
    u = __hip_atomic_load(p, __ATOMIC_RELAXED, __HIP_MEMORY_SCOPE_AGENT);
  }
  union { unsigned u32; float f; } c;
  c.u32 = (unsigned)u;
  return c.f;
}

// Zero ticket + all packed-carry words (workspace is poisoned每 iteration).
extern "C" __global__ __launch_bounds__(256) void ewrls_init(
    unsigned long long* __restrict__ cw, unsigned* __restrict__ tk) {
  size_t i = (size_t)blockIdx.x * 256 + threadIdx.x;
  if (i < kCarryU64) cw[i] = 0ull;
  if (i == 0) *tk = 0u;
}

// Single-pass chunked scan, decoupled lookback, fence-free.
// chunk id c = j*kB + b; block ticket T owns chunks {2T, 2T+1} (same j).
extern "C" __global__ __launch_bounds__(256) void ewrls_fused(
    const float* __restrict__ x, const float* __restrict__ zl,
    unsigned* __restrict__ ws, float* __restrict__ y) {
  __shared__ unsigned sh_t;
  if (threadIdx.x == 0)
    sh_t = __hip_atomic_fetch_add(ws, 1u, __ATOMIC_RELAXED,
                                  __HIP_MEMORY_SCOPE_AGENT);
  __syncthreads();
  const unsigned T = sh_t;
  const int c = (int)(2u * T) + (int)(threadIdx.x >> 7);
  const int j = c >> 6;                // c / kB
  const int b = c & 63;                // c % kB
  const int cv = threadIdx.x & 127;

  unsigned long long* __restrict__ carry =
      reinterpret_cast<unsigned long long*>(
          reinterpret_cast<char*>(ws) + kCarryOffB);

  float lam[4];
  load_lam(zl, cv * 4, lam);

  // Phase A: local decayed aggregate. CACHING loads (want x in L2/L3 for
  // phase B's re-read).
  const size_t base = ((size_t)b * kT + (size_t)j * kL) * kCV + cv;
  const vfloat4* xp = reinterpret_cast<const vfloat4*>(x) + base;
  float a0 = 0.f, a1 = 0.f, a2 = 0.f, a3 = 0.f;
#pragma unroll 8
  for (int t = 0; t < kL; ++t) {
    vfloat4 v = xp[(size_t)t * kCV];
    a0 = fmaf(lam[0], a0, v.x);
    a1 = fmaf(lam[1], a1, v.y);
    a2 = fmaf(lam[2], a2, v.z);
    a3 = fmaf(lam[3], a3, v.w);
  }

  // Publish: packed (1<<32 | bits) relaxed agent atomics. No fence needed —
  // flag and value are one atom.
  {
    unsigned long long* cp = carry + (((size_t)c * kCV + cv) << 2);
    union { float f; unsigned u; } q;
    q.f = a0;
    __hip_atomic_store(cp + 0, (1ull << 32) | q.u, __ATOMIC_RELAXED,
                       __HIP_MEMORY_SCOPE_AGENT);
    q.f = a1;
    __hip_atomic_store(cp + 1, (1ull << 32) | q.u, __ATOMIC_RELAXED,
                       __HIP_MEMORY_SCOPE_AGENT);
    q.f = a2;
    __hip_atomic_store(cp + 2, (1ull << 32) | q.u, __ATOMIC_RELAXED,
                       __HIP_MEMORY_SCOPE_AGENT);
    q.f = a3;
    __hip_atomic_store(cp + 3, (1ull << 32) | q.u, __ATOMIC_RELAXED,
                       __HIP_MEMORY_SCOPE_AGENT);
  }

  // lam^kL (kL = 64 -> 6 squarings).
  float lamL[4];
#pragma unroll
  for (int k = 0; k < 4; ++k) {
    float p = lam[k];
#pragma unroll
    for (int q = 0; q < 6; ++q) p = p * p;
    lamL[k] = p;
  }

  // Lookback: fold predecessor aggregates (ascending i = verified fold).
  float S0 = 0.f, S1 = 0.f, S2 = 0.f, S3 = 0.f;
  float p0 = 1.f, p1 = 1.f, p2 = 1.f, p3 = 1.f;
  for (int i = 0; i < j; ++i) {
    const unsigned long long* cp =
        carry + ((((size_t)i * kB + b) * kCV + cv) << 2);
    float v0 = poll_val(cp + 0);
    float v1 = poll_val(cp + 1);
    float v2 = poll_val(cp + 2);
    float v3 = poll_val(cp + 3);
    S0 = fmaf(lamL[0], S0, v0);
    S1 = fmaf(lamL[1], S1, v1);
    S2 = fmaf(lamL[2], S2, v2);
    S3 = fmaf(lamL[3], S3, v3);
    p0 *= lamL[0];
    p1 *= lamL[1];
    p2 *= lamL[2];
    p3 *= lamL[3];
  }

  // Seed Q closed-form: Q_{j*kL-1} = (1 - lam^(j*kL)) / (1 - lam).
  float Q0 = (1.0f - p0) * __builtin_amdgcn_rcpf(1.0f - lam[0]);
  float Q1 = (1.0f - p1) * __builtin_amdgcn_rcpf(1.0f - lam[1]);
  float Q2 = (1.0f - p2) * __builtin_amdgcn_rcpf(1.0f - lam[2]);
  float Q3 = (1.0f - p3) * __builtin_amdgcn_rcpf(1.0f - lam[3]);

  // Phase B: re-read x (nt: evict-first, it's L2/L3-hot), scan, nt store.
  vfloat4* yp = reinterpret_cast<vfloat4*>(y) + base;
#pragma unroll 8
  for (int t = 0; t < kL; ++t) {
    vfloat4 v = __builtin_nontemporal_load(&xp[(size_t)t * kCV]);
    S0 = fmaf(lam[0], S0, v.x);
    S1 = fmaf(lam[1], S1, v.y);
    S2 = fmaf(lam[2], S2, v.z);
    S3 = fmaf(lam[3], S3, v.w);
    Q0 = fmaf(lam[0], Q0, 1.0f);
    Q1 = fmaf(lam[1], Q1, 1.0f);
    Q2 = fmaf(lam[2], Q2, 1.0f);
    Q3 = fmaf(lam[3], Q3, 1.0f);
    vfloat4 o;
    o.x = S0 * __builtin_amdgcn_rcpf(Q0);
    o.y = S1 * __builtin_amdgcn_rcpf(Q1);
    o.z = S2 * __builtin_amdgcn_rcpf(Q2);
    o.w = S3 * __builtin_amdgcn_rcpf(Q3);
    __builtin_nontemporal_store(o, &yp[(size_t)t * kCV]);
  }
}

// Fallback if workspace is too small: fully sequential over T per (b, 4ch).
extern "C" __global__ __launch_bounds__(256) void ewrls_serial(
    const float* __restrict__ x, const float* __restrict__ zl,
    float* __restrict__ y) {
  int idx = blockIdx.x * 256 + threadIdx.x;   // [0, kB*kCV)
  int cv = idx % kCV;
  int b = idx / kCV;
  float lam[4];
  load_lam(zl, cv * 4, lam);
  float S[4] = {0.f, 0.f, 0.f, 0.f};
  float Q[4] = {0.f, 0.f, 0.f, 0.f};
  const size_t base = (size_t)b * kT * kCV + cv;
  const vfloat4* xp = reinterpret_cast<const vfloat4*>(x) + base;
  vfloat4* yp = reinterpret_cast<vfloat4*>(y) + base;
#pragma unroll 4
  for (int t = 0; t < kT; ++t) {
    vfloat4 v = xp[(size_t)t * kCV];
    S[0] = fmaf(lam[0], S[0], v.x);
    S[1] = fmaf(lam[1], S[1], v.y);
    S[2] = fmaf(lam[2], S[2], v.z);
    S[3] = fmaf(lam[3], S[3], v.w);
    Q[0] = fmaf(lam[0], Q[0], 1.0f);
    Q[1] = fmaf(lam[1], Q[1], 1.0f);
    Q[2] = fmaf(lam[2], Q[2], 1.0f);
    Q[3] = fmaf(lam[3], Q[3], 1.0f);
    vfloat4 o;
    o.x = S[0] * __builtin_amdgcn_rcpf(Q[0]);
    o.y = S[1] * __builtin_amdgcn_rcpf(Q[1]);
    o.z = S[2] * __builtin_amdgcn_rcpf(Q[2]);
    o.w = S[3] * __builtin_amdgcn_rcpf(Q[3]);
    yp[(size_t)t * kCV] = o;
  }
}

extern "C" void kernel_launch(void* const* d_in, const int* in_sizes, int n_in,
                              void* d_out, int out_size, void* d_ws,
                              size_t ws_size, hipStream_t stream) {
  const float* x = (const float*)d_in[0];
  const float* zl = (const float*)d_in[1];
  float* y = (float*)d_out;

  const size_t need = kCarryOffB + kCarryU64 * 8;  // ~4.06 MiB
  if (ws_size >= need) {
    unsigned* ws = (unsigned*)d_ws;
    unsigned long long* cw = reinterpret_cast<unsigned long long*>(
        reinterpret_cast<char*>(d_ws) + kCarryOffB);
    ewrls_init<<<(int)((kCarryU64 + 255) / 256), 256, 0, stream>>>(cw, ws);
    ewrls_fused<<<kBlocks, 256, 0, stream>>>(x, zl, ws, y);
  } else {
    const int n = kB * kCV;                 // 8192 -> 32 blocks
    ewrls_serial<<<n / 256, 256, 0, stream>>>(x, zl, y);
  }
}